// Round 9
// baseline (2075.736 us; speedup 1.0000x reference)
//
#include <hip/hip_runtime.h>

// GRU: B=128, T=2048, H=128.
// Kernel 1 (gru_proj): xz/xr/xh = x @ W^T + b via bf16 MFMA 16x16x32.
// Kernel 2 (gru_rec1b): 1 batch/block x 128 blocks, 2 waves, ONE barrier/step.
//   Each wave computes the r gate for ALL 128 units redundantly (8 tiles,
//   U_r fully register-resident) -> rh assembly is intra-wave into a
//   wave-private LDS buffer (lgkmcnt only, no s_barrier). h exchange is the
//   single cross-wave handoff: double-buffered hx[t&1] + one barrier/step.
//   z-MFMAs issue under the rh read latency. 2-deep global prefetch +
//   fire-and-forget h stores (vmcnt never drained in loop).

#define T_LEN 2048
#define H_DIM 128

typedef __attribute__((ext_vector_type(8))) __bf16 bf16x8;
typedef __attribute__((ext_vector_type(4))) float f32x4;

// raw barrier: drains LDS ops (cross-wave visibility) but NOT vmcnt. [m201]
#define BARRIER() asm volatile("s_waitcnt lgkmcnt(0)\n\ts_barrier" ::: "memory")
// intra-wave LDS write->read fence (DS is in-order per wave; belt+braces)
#define LGKM0() asm volatile("s_waitcnt lgkmcnt(0)" ::: "memory")

__device__ __forceinline__ unsigned short f2bf_bits(float f){
  __bf16 b = (__bf16)f;                     // fptrunc, RNE
  return __builtin_bit_cast(unsigned short, b);
}
__device__ __forceinline__ float bf2f(unsigned short s){
  unsigned int u = ((unsigned int)s) << 16;
  return __builtin_bit_cast(float, u);
}
// hardware v_exp_f32 / v_rcp_f32 (no precise-division sequence)
__device__ __forceinline__ float sigm(float x){
  float e = __builtin_amdgcn_exp2f(-1.4426950408889634f * x);
  return __builtin_amdgcn_rcpf(1.0f + e);
}
__device__ __forceinline__ float tanh_fast(float x){
  float e = __builtin_amdgcn_exp2f(2.8853900817779268f * x);  // e^(2x)
  return 1.0f - 2.0f * __builtin_amdgcn_rcpf(e + 1.0f);       // inf-safe
}

// ---------------- projection GEMM (unchanged, verified) ----------------

__device__ __forceinline__ void stage_mat128(const float* __restrict__ src,
                                             __bf16 (*dst)[136], int tid){
  #pragma unroll
  for (int rep = 0; rep < 8; ++rep){
    int fi = rep * 2048 + tid * 4;
    float4 v = *reinterpret_cast<const float4*>(src + fi);
    int m = fi >> 7;
    int k = fi & 127;
    unsigned long long pk =
        (unsigned long long)f2bf_bits(v.x)
      | ((unsigned long long)f2bf_bits(v.y) << 16)
      | ((unsigned long long)f2bf_bits(v.z) << 32)
      | ((unsigned long long)f2bf_bits(v.w) << 48);
    *reinterpret_cast<unsigned long long*>(&dst[m][k]) = pk;
  }
}

__global__ __launch_bounds__(512, 2) void gru_proj(
    const float* __restrict__ x,
    const float* __restrict__ Wz, const float* __restrict__ Wr, const float* __restrict__ Wh,
    const float* __restrict__ bz, const float* __restrict__ br, const float* __restrict__ bh,
    unsigned int* __restrict__ out_zr, unsigned short* __restrict__ out_h)
{
  __shared__ __bf16 xs[128][136];
  __shared__ __bf16 wsh[3][128][136];

  const int tid = threadIdx.x;
  const long Mbase = (long)blockIdx.x * 128;

  stage_mat128(x + Mbase * H_DIM, xs, tid);
  stage_mat128(Wz, wsh[0], tid);
  stage_mat128(Wr, wsh[1], tid);
  stage_mat128(Wh, wsh[2], tid);
  __syncthreads();

  const int w  = tid >> 6, l = tid & 63;
  const int ml = l & 15;
  const int kl = (l >> 4) * 8;
  const int n  = w * 16 + ml;

  bf16x8 bfr[3][4];
  #pragma unroll
  for (int g = 0; g < 3; ++g)
    #pragma unroll
    for (int kk = 0; kk < 4; ++kk)
      bfr[g][kk] = *reinterpret_cast<const bf16x8*>(&wsh[g][n][kk * 32 + kl]);

  const float bzv = bz[n], brv = br[n], bhv = bh[n];

  f32x4 acc[8][3];
  #pragma unroll
  for (int mt = 0; mt < 8; ++mt)
    #pragma unroll
    for (int g = 0; g < 3; ++g)
      acc[mt][g] = (f32x4){0.f, 0.f, 0.f, 0.f};

  #pragma unroll
  for (int mt = 0; mt < 8; ++mt){
    #pragma unroll
    for (int kk = 0; kk < 4; ++kk){
      bf16x8 a = *reinterpret_cast<const bf16x8*>(&xs[mt * 16 + ml][kk * 32 + kl]);
      acc[mt][0] = __builtin_amdgcn_mfma_f32_16x16x32_bf16(a, bfr[0][kk], acc[mt][0], 0, 0, 0);
      acc[mt][1] = __builtin_amdgcn_mfma_f32_16x16x32_bf16(a, bfr[1][kk], acc[mt][1], 0, 0, 0);
      acc[mt][2] = __builtin_amdgcn_mfma_f32_16x16x32_bf16(a, bfr[2][kk], acc[mt][2], 0, 0, 0);
    }
  }

  #pragma unroll
  for (int mt = 0; mt < 8; ++mt){
    #pragma unroll
    for (int p = 0; p < 4; ++p){
      long row = Mbase + mt * 16 + (l >> 4) * 4 + p;
      float vz = acc[mt][0][p] + bzv;
      float vr = acc[mt][1][p] + brv;
      float vh = acc[mt][2][p] + bhv;
      unsigned int word = (unsigned int)f2bf_bits(vz)
                        | (((unsigned int)f2bf_bits(vr)) << 16);
      out_zr[row * H_DIM + n] = word;
      out_h [row * H_DIM + n] = f2bf_bits(vh);
    }
  }
}

// ---- recurrence: redundant-r, single barrier/step, 2 waves, 1 batch/block --

__device__ __forceinline__ bf16x8 ld_u_frag(const float* p){
  float4 a = *reinterpret_cast<const float4*>(p);
  float4 b = *reinterpret_cast<const float4*>(p + 4);
  bf16x8 r;
  r[0]=(__bf16)a.x; r[1]=(__bf16)a.y; r[2]=(__bf16)a.z; r[3]=(__bf16)a.w;
  r[4]=(__bf16)b.x; r[5]=(__bf16)b.y; r[6]=(__bf16)b.z; r[7]=(__bf16)b.w;
  return r;
}

#define MFMA(A, B, C) __builtin_amdgcn_mfma_f32_16x16x32_bf16(A, B, C, 0, 0, 0)

__device__ __forceinline__ void gru_step1b(
    int t, int w, int g8, int c16, int ub_own, int ubg16,
    const bf16x8 (*ufr)[4], const bf16x8 (*ufz)[4], const bf16x8 (*ufh)[4],
    const __bf16* cur, __bf16* nxt, __bf16* myrhx,
    const unsigned int* xzr, const unsigned short* xh, float* out,
    unsigned int& zr1, unsigned int& zr2, unsigned short& xhw, float& h_own)
{
  const f32x4 zero = (f32x4){0.f, 0.f, 0.f, 0.f};
  const int tp = (t + 2 < T_LEN) ? t + 2 : T_LEN - 1;

  // ---- phase A: h reads + r gate for ALL 128 units ----
  bf16x8 a0 = *reinterpret_cast<const bf16x8*>(&cur[      g8 * 8]);
  bf16x8 a1 = *reinterpret_cast<const bf16x8*>(&cur[32  + g8 * 8]);
  bf16x8 a2 = *reinterpret_cast<const bf16x8*>(&cur[64  + g8 * 8]);
  bf16x8 a3 = *reinterpret_cast<const bf16x8*>(&cur[96  + g8 * 8]);
  __bf16 hg1 = cur[16 * g8 + c16];        // h for assigned tile g8
  __bf16 hg2 = cur[64 + 16 * g8 + c16];   // h for assigned tile g8+4

  f32x4 racc[8];
  #pragma unroll
  for (int i = 0; i < 8; ++i) racc[i] = MFMA(a0, ufr[i][0], zero);
  #pragma unroll
  for (int i = 0; i < 8; ++i) racc[i] = MFMA(a1, ufr[i][1], racc[i]);
  #pragma unroll
  for (int i = 0; i < 8; ++i) racc[i] = MFMA(a2, ufr[i][2], racc[i]);
  #pragma unroll
  for (int i = 0; i < 8; ++i) racc[i] = MFMA(a3, ufr[i][3], racc[i]);

  // select this lane-group's two assigned tiles {g8, g8+4}
  float ra = racc[0][0];
  ra = (g8 == 1) ? racc[1][0] : ra;
  ra = (g8 == 2) ? racc[2][0] : ra;
  ra = (g8 == 3) ? racc[3][0] : ra;
  float rb = racc[4][0];
  rb = (g8 == 1) ? racc[5][0] : rb;
  rb = (g8 == 2) ? racc[6][0] : rb;
  rb = (g8 == 3) ? racc[7][0] : rb;

  float xr1 = __builtin_bit_cast(float, zr1 & 0xffff0000u);
  float xr2 = __builtin_bit_cast(float, zr2 & 0xffff0000u);
  float rh1 = sigm(xr1 + ra) * (float)hg1;
  float rh2 = sigm(xr2 + rb) * (float)hg2;
  myrhx[16 * g8 + c16]      = (__bf16)rh1;   // 2-way same-dword b16: free
  myrhx[64 + 16 * g8 + c16] = (__bf16)rh2;
  LGKM0();                                   // own writes -> own reads

  // ---- phase B: rh frags + z (hides under read latency) + h~ + update ----
  bf16x8 b0 = *reinterpret_cast<const bf16x8*>(&myrhx[      g8 * 8]);
  bf16x8 b1 = *reinterpret_cast<const bf16x8*>(&myrhx[32  + g8 * 8]);
  bf16x8 b2 = *reinterpret_cast<const bf16x8*>(&myrhx[64  + g8 * 8]);
  bf16x8 b3 = *reinterpret_cast<const bf16x8*>(&myrhx[96  + g8 * 8]);

  f32x4 zacc[4];
  #pragma unroll
  for (int j = 0; j < 4; ++j) zacc[j] = MFMA(a0, ufz[j][0], zero);
  #pragma unroll
  for (int j = 0; j < 4; ++j) zacc[j] = MFMA(a1, ufz[j][1], zacc[j]);
  #pragma unroll
  for (int j = 0; j < 4; ++j) zacc[j] = MFMA(a2, ufz[j][2], zacc[j]);
  #pragma unroll
  for (int j = 0; j < 4; ++j) zacc[j] = MFMA(a3, ufz[j][3], zacc[j]);

  f32x4 hacc[4];
  #pragma unroll
  for (int j = 0; j < 4; ++j) hacc[j] = MFMA(b0, ufh[j][0], zero);
  #pragma unroll
  for (int j = 0; j < 4; ++j) hacc[j] = MFMA(b1, ufh[j][1], hacc[j]);
  #pragma unroll
  for (int j = 0; j < 4; ++j) hacc[j] = MFMA(b2, ufh[j][2], hacc[j]);
  #pragma unroll
  for (int j = 0; j < 4; ++j) hacc[j] = MFMA(b3, ufh[j][3], hacc[j]);

  float zs = zacc[0][0];
  zs = (g8 == 1) ? zacc[1][0] : zs;
  zs = (g8 == 2) ? zacc[2][0] : zs;
  zs = (g8 == 3) ? zacc[3][0] : zs;
  float hs = hacc[0][0];
  hs = (g8 == 1) ? hacc[1][0] : hs;
  hs = (g8 == 2) ? hacc[2][0] : hs;
  hs = (g8 == 3) ? hacc[3][0] : hs;

  unsigned int zro = (w != 0) ? zr2 : zr1;           // own tile = 4w + g8
  float xz = __builtin_bit_cast(float, zro << 16);
  float zg = sigm(xz + zs);
  float hc = tanh_fast(bf2f(xhw) + hs);
  float hn = fmaf(zg, hc - h_own, h_own);            // (1-z)h + z*hc
  h_own = hn;
  nxt[64 * w + 16 * g8 + c16] = (__bf16)hn;
  out[ub_own + t * H_DIM] = hn;                      // fire-and-forget

  zr1 = xzr[ubg16 + tp * H_DIM];                     // refill for t+2
  zr2 = xzr[ubg16 + 64 + tp * H_DIM];
  xhw = xh[ub_own + tp * H_DIM];
  BARRIER();                                         // the ONLY barrier/step
}

__global__ __launch_bounds__(128, 1) void gru_rec1b(
    const float* __restrict__ Uz, const float* __restrict__ Ur, const float* __restrict__ Uh,
    const int* __restrict__ lengths,
    const unsigned int* xzr,            // aliases `out` (packed bf16 xz|xr)
    const unsigned short* __restrict__ xh,
    float* out)
{
  __shared__ __align__(16) __bf16 hx0[H_DIM];   // h double buffer
  __shared__ __align__(16) __bf16 hx1[H_DIM];
  __shared__ __align__(16) __bf16 rhxw[2][H_DIM];  // per-wave rh buffer

  const int tid = threadIdx.x;
  const int w = tid >> 6, l = tid & 63;
  const int g8  = l >> 4;
  const int c16 = l & 15;
  const int b   = blockIdx.x;
  const int len = lengths[b];

  // U_r for ALL 8 tiles (128 VGPR); U_z/U_h for own wave's 4 tiles (64+64)
  bf16x8 ufr[8][4];
  #pragma unroll
  for (int t8 = 0; t8 < 8; ++t8){
    const int n = 16 * t8 + c16;
    #pragma unroll
    for (int c = 0; c < 4; ++c)
      ufr[t8][c] = ld_u_frag(Ur + n * H_DIM + c * 32 + g8 * 8);
  }
  bf16x8 ufz[4][4], ufh[4][4];
  #pragma unroll
  for (int j = 0; j < 4; ++j){
    const int n = 64 * w + 16 * j + c16;
    #pragma unroll
    for (int c = 0; c < 4; ++c){
      ufz[j][c] = ld_u_frag(Uz + n * H_DIM + c * 32 + g8 * 8);
      ufh[j][c] = ld_u_frag(Uh + n * H_DIM + c * 32 + g8 * 8);
    }
  }

  const int n_own  = 64 * w + 16 * g8 + c16;
  const int ub_own = b * (T_LEN * H_DIM) + n_own;
  const int ubg16  = b * (T_LEN * H_DIM) + 16 * g8 + c16;  // xr for tile g8 (+64 for g8+4)

  if (tid < 64) reinterpret_cast<unsigned int*>(hx0)[tid] = 0u;  // h0 = 0
  float h_own = 0.f;
  __syncthreads();

  __bf16* myrhx = rhxw[w];

  // 2-deep prefetch, named regs
  unsigned int  zr1A = xzr[ubg16],            zr1B = xzr[ubg16 + H_DIM];
  unsigned int  zr2A = xzr[ubg16 + 64],       zr2B = xzr[ubg16 + 64 + H_DIM];
  unsigned short xhA = xh[ub_own],            xhB = xh[ub_own + H_DIM];

  int t = 0;
  for (; t + 1 < len; t += 2){
    gru_step1b(t,   w, g8, c16, ub_own, ubg16, ufr, ufz, ufh,
               hx0, hx1, myrhx, xzr, xh, out, zr1A, zr2A, xhA, h_own);
    gru_step1b(t+1, w, g8, c16, ub_own, ubg16, ufr, ufz, ufh,
               hx1, hx0, myrhx, xzr, xh, out, zr1B, zr2B, xhB, h_own);
  }
  if (t < len){
    gru_step1b(t,   w, g8, c16, ub_own, ubg16, ufr, ufz, ufh,
               hx0, hx1, myrhx, xzr, xh, out, zr1A, zr2A, xhA, h_own);
  }

  // masked region: exact zeros for t >= len (disjoint from h-stores)
  const long base = (long)b * (T_LEN * H_DIM);
  for (long i = (long)len * H_DIM + tid * 4; i < (long)T_LEN * H_DIM; i += 128 * 4){
    *reinterpret_cast<float4*>(out + base + i) = make_float4(0.f, 0.f, 0.f, 0.f);
  }
}

extern "C" void kernel_launch(void* const* d_in, const int* in_sizes, int n_in,
                              void* d_out, int out_size, void* d_ws, size_t ws_size,
                              hipStream_t stream){
  const float* x       = (const float*)d_in[0];
  const int*   lengths = (const int*)  d_in[1];
  const float* Wz = (const float*)d_in[2];
  const float* Uz = (const float*)d_in[3];
  const float* bz = (const float*)d_in[4];
  const float* Wr = (const float*)d_in[5];
  const float* Ur = (const float*)d_in[6];
  const float* br = (const float*)d_in[7];
  const float* Wh = (const float*)d_in[8];
  const float* Uh = (const float*)d_in[9];
  const float* bh = (const float*)d_in[10];

  unsigned int*   zr    = (unsigned int*)d_out;   // packed bf16 xz|xr, then h
  unsigned short* xhbuf = (unsigned short*)d_ws;  // bf16 xh

  gru_proj<<<dim3(2048), dim3(512), 0, stream>>>(x, Wz, Wr, Wh, bz, br, bh, zr, xhbuf);
  gru_rec1b<<<dim3(128), dim3(128), 0, stream>>>(Uz, Ur, Uh, lengths, zr, xhbuf, (float*)d_out);
}

// Round 10
// 1797.462 us; speedup vs baseline: 1.1548x; 1.1548x over previous
//
#include <hip/hip_runtime.h>

// GRU: B=128, T=2048, H=128.
// K1 gru_proj: xz/xr/xh = x @ W^T + b via bf16 MFMA (verified since R1).
// K2 gru_recb: 8 batches/block x 16 blocks, 4 waves x 32 units. Batches live
//   in the MFMA A-ROWS (h tile [8][136] bf16 in LDS; rows 8-15 of the A
//   matrix read rows 0-7 again -> row-groups split the epilogue units).
//   Per wave per phase: 4 ds_read_b128 serve 8 batches (vs broadcast-A's
//   4 reads per batch) -> LDS pipe load halves while compute is 8x denser.
//   Lane (g8,p,c) owns batch 4*(g8&1)+p, unit 32w+16*(g8>>1)+c.
//   dpp-xor1 packed dword LDS writes (conflict-free banks). 2 lgkm-only
//   barriers/step; z-MFMAs issue on register A-frags under rh-read latency;
//   2-deep global prefetch; vmcnt never drained; out-of-range stores are
//   overwritten by K3 gru_tail (kernel-boundary ordering).

#define T_LEN 2048
#define H_DIM 128
#define TH    262144u   // T_LEN*H_DIM

typedef __attribute__((ext_vector_type(8))) __bf16 bf16x8;
typedef __attribute__((ext_vector_type(4))) float f32x4;

#define BARRIER() asm volatile("s_waitcnt lgkmcnt(0)\n\ts_barrier" ::: "memory")

__device__ __forceinline__ unsigned short f2bf_bits(float f){
  __bf16 b = (__bf16)f;                     // fptrunc, RNE
  return __builtin_bit_cast(unsigned short, b);
}
__device__ __forceinline__ float bf2f(unsigned short s){
  unsigned int u = ((unsigned int)s) << 16;
  return __builtin_bit_cast(float, u);
}
__device__ __forceinline__ float sigm(float x){
  float e = __builtin_amdgcn_exp2f(-1.4426950408889634f * x);
  return __builtin_amdgcn_rcpf(1.0f + e);
}
__device__ __forceinline__ float tanh_fast(float x){
  float e = __builtin_amdgcn_exp2f(2.8853900817779268f * x);  // e^(2x)
  return 1.0f - 2.0f * __builtin_amdgcn_rcpf(e + 1.0f);       // inf-safe
}
__device__ __forceinline__ unsigned int dpp_xor1_u32(unsigned int x){
  return (unsigned int)__builtin_amdgcn_update_dpp(0, (int)x, 0xB1, 0xF, 0xF, true);
}

// ---------------- projection GEMM (unchanged, verified) ----------------

__device__ __forceinline__ void stage_mat128(const float* __restrict__ src,
                                             __bf16 (*dst)[136], int tid){
  #pragma unroll
  for (int rep = 0; rep < 8; ++rep){
    int fi = rep * 2048 + tid * 4;
    float4 v = *reinterpret_cast<const float4*>(src + fi);
    int m = fi >> 7;
    int k = fi & 127;
    unsigned long long pk =
        (unsigned long long)f2bf_bits(v.x)
      | ((unsigned long long)f2bf_bits(v.y) << 16)
      | ((unsigned long long)f2bf_bits(v.z) << 32)
      | ((unsigned long long)f2bf_bits(v.w) << 48);
    *reinterpret_cast<unsigned long long*>(&dst[m][k]) = pk;
  }
}

__global__ __launch_bounds__(512, 2) void gru_proj(
    const float* __restrict__ x,
    const float* __restrict__ Wz, const float* __restrict__ Wr, const float* __restrict__ Wh,
    const float* __restrict__ bz, const float* __restrict__ br, const float* __restrict__ bh,
    unsigned int* __restrict__ out_zr, unsigned short* __restrict__ out_h)
{
  __shared__ __bf16 xs[128][136];
  __shared__ __bf16 wsh[3][128][136];

  const int tid = threadIdx.x;
  const long Mbase = (long)blockIdx.x * 128;

  stage_mat128(x + Mbase * H_DIM, xs, tid);
  stage_mat128(Wz, wsh[0], tid);
  stage_mat128(Wr, wsh[1], tid);
  stage_mat128(Wh, wsh[2], tid);
  __syncthreads();

  const int w  = tid >> 6, l = tid & 63;
  const int ml = l & 15;
  const int kl = (l >> 4) * 8;
  const int n  = w * 16 + ml;

  bf16x8 bfr[3][4];
  #pragma unroll
  for (int g = 0; g < 3; ++g)
    #pragma unroll
    for (int kk = 0; kk < 4; ++kk)
      bfr[g][kk] = *reinterpret_cast<const bf16x8*>(&wsh[g][n][kk * 32 + kl]);

  const float bzv = bz[n], brv = br[n], bhv = bh[n];

  f32x4 acc[8][3];
  #pragma unroll
  for (int mt = 0; mt < 8; ++mt)
    #pragma unroll
    for (int g = 0; g < 3; ++g)
      acc[mt][g] = (f32x4){0.f, 0.f, 0.f, 0.f};

  #pragma unroll
  for (int mt = 0; mt < 8; ++mt){
    #pragma unroll
    for (int kk = 0; kk < 4; ++kk){
      bf16x8 a = *reinterpret_cast<const bf16x8*>(&xs[mt * 16 + ml][kk * 32 + kl]);
      acc[mt][0] = __builtin_amdgcn_mfma_f32_16x16x32_bf16(a, bfr[0][kk], acc[mt][0], 0, 0, 0);
      acc[mt][1] = __builtin_amdgcn_mfma_f32_16x16x32_bf16(a, bfr[1][kk], acc[mt][1], 0, 0, 0);
      acc[mt][2] = __builtin_amdgcn_mfma_f32_16x16x32_bf16(a, bfr[2][kk], acc[mt][2], 0, 0, 0);
    }
  }

  #pragma unroll
  for (int mt = 0; mt < 8; ++mt){
    #pragma unroll
    for (int p = 0; p < 4; ++p){
      long row = Mbase + mt * 16 + (l >> 4) * 4 + p;
      float vz = acc[mt][0][p] + bzv;
      float vr = acc[mt][1][p] + brv;
      float vh = acc[mt][2][p] + bhv;
      unsigned int word = (unsigned int)f2bf_bits(vz)
                        | (((unsigned int)f2bf_bits(vr)) << 16);
      out_zr[row * H_DIM + n] = word;
      out_h [row * H_DIM + n] = f2bf_bits(vh);
    }
  }
}

// ---- recurrence: batches-in-rows MFMA, 4 waves, 8 batches/block ----

__device__ __forceinline__ bf16x8 ld_u_frag(const float* p){
  float4 a = *reinterpret_cast<const float4*>(p);
  float4 b = *reinterpret_cast<const float4*>(p + 4);
  bf16x8 r;
  r[0]=(__bf16)a.x; r[1]=(__bf16)a.y; r[2]=(__bf16)a.z; r[3]=(__bf16)a.w;
  r[4]=(__bf16)b.x; r[5]=(__bf16)b.y; r[6]=(__bf16)b.z; r[7]=(__bf16)b.w;
  return r;
}

#define MFMA(A, B, C) __builtin_amdgcn_mfma_f32_16x16x32_bf16(A, B, C, 0, 0, 0)

__device__ __forceinline__ void gru_stepX(
    int t, int row, int g8, int tsel,
    const bf16x8 (*ufz)[4], const bf16x8 (*ufr)[4], const bf16x8 (*ufh)[4],
    __bf16 (*hbf)[136], __bf16 (*rhbf)[136],
    unsigned int* hb32, unsigned int* rb32, int wdw, bool wlane,
    const unsigned int* xzr, const unsigned short* xh, float* out,
    const unsigned int* ob,
    unsigned int* zrw, unsigned int* xhw, float* h_own)
{
  const f32x4 zero = (f32x4){0.f, 0.f, 0.f, 0.f};
  const int tp = (t + 2 < T_LEN) ? t + 2 : T_LEN - 1;

  // ---- phase A: r gate for 8 batches x this wave's 32 units ----
  bf16x8 a0 = *reinterpret_cast<const bf16x8*>(&hbf[row][ 0 + g8 * 8]);
  bf16x8 a1 = *reinterpret_cast<const bf16x8*>(&hbf[row][32 + g8 * 8]);
  bf16x8 a2 = *reinterpret_cast<const bf16x8*>(&hbf[row][64 + g8 * 8]);
  bf16x8 a3 = *reinterpret_cast<const bf16x8*>(&hbf[row][96 + g8 * 8]);

  f32x4 r0a = MFMA(a1, ufr[0][1], MFMA(a0, ufr[0][0], zero));
  f32x4 r0b = MFMA(a3, ufr[0][3], MFMA(a2, ufr[0][2], zero));
  f32x4 r1a = MFMA(a1, ufr[1][1], MFMA(a0, ufr[1][0], zero));
  f32x4 r1b = MFMA(a3, ufr[1][3], MFMA(a2, ufr[1][2], zero));
  f32x4 rs0 = r0a + r0b;
  f32x4 rs1 = r1a + r1b;
  f32x4 rsel = tsel ? rs1 : rs0;

  unsigned int rw[4];
  #pragma unroll
  for (int p = 0; p < 4; ++p){
    float xr = __builtin_bit_cast(float, zrw[p] & 0xffff0000u);
    float rg = sigm(xr + rsel[p]);
    unsigned int bits = (unsigned int)f2bf_bits(rg * h_own[p]);
    rw[p] = bits | (dpp_xor1_u32(bits) << 16);   // all lanes run dpp (exec!)
  }
  if (wlane){
    rb32[wdw +   0] = rw[0];
    rb32[wdw +  68] = rw[1];
    rb32[wdw + 136] = rw[2];
    rb32[wdw + 204] = rw[3];
  }
  BARRIER();                                     // rh visible

  // ---- phase B: z on register A-frags (hides rh-read) + h~ + update ----
  bf16x8 b0 = *reinterpret_cast<const bf16x8*>(&rhbf[row][ 0 + g8 * 8]);
  bf16x8 b1 = *reinterpret_cast<const bf16x8*>(&rhbf[row][32 + g8 * 8]);
  bf16x8 b2 = *reinterpret_cast<const bf16x8*>(&rhbf[row][64 + g8 * 8]);
  bf16x8 b3 = *reinterpret_cast<const bf16x8*>(&rhbf[row][96 + g8 * 8]);

  f32x4 z0a = MFMA(a1, ufz[0][1], MFMA(a0, ufz[0][0], zero));
  f32x4 z0b = MFMA(a3, ufz[0][3], MFMA(a2, ufz[0][2], zero));
  f32x4 z1a = MFMA(a1, ufz[1][1], MFMA(a0, ufz[1][0], zero));
  f32x4 z1b = MFMA(a3, ufz[1][3], MFMA(a2, ufz[1][2], zero));
  f32x4 zs0 = z0a + z0b;
  f32x4 zs1 = z1a + z1b;
  f32x4 zsel = tsel ? zs1 : zs0;

  f32x4 h0a = MFMA(b1, ufh[0][1], MFMA(b0, ufh[0][0], zero));
  f32x4 h0b = MFMA(b3, ufh[0][3], MFMA(b2, ufh[0][2], zero));
  f32x4 h1a = MFMA(b1, ufh[1][1], MFMA(b0, ufh[1][0], zero));
  f32x4 h1b = MFMA(b3, ufh[1][3], MFMA(b2, ufh[1][2], zero));
  f32x4 hs0 = h0a + h0b;
  f32x4 hs1 = h1a + h1b;
  f32x4 hsel = tsel ? hs1 : hs0;

  const unsigned int tof = (unsigned int)t * H_DIM;
  unsigned int hw[4];
  #pragma unroll
  for (int p = 0; p < 4; ++p){
    float xz = __builtin_bit_cast(float, zrw[p] << 16);
    float zg = sigm(xz + zsel[p]);
    float hc = tanh_fast(bf2f((unsigned short)xhw[p]) + hsel[p]);
    float hn = fmaf(zg, hc - h_own[p], h_own[p]);   // (1-z)h + z*hc
    h_own[p] = hn;
    out[ob[p] + tof] = hn;                          // fire-and-forget
    unsigned int bits = (unsigned int)f2bf_bits(hn);
    hw[p] = bits | (dpp_xor1_u32(bits) << 16);
  }
  if (wlane){
    hb32[wdw +   0] = hw[0];
    hb32[wdw +  68] = hw[1];
    hb32[wdw + 136] = hw[2];
    hb32[wdw + 204] = hw[3];
  }
  const unsigned int pof = (unsigned int)tp * H_DIM;
  #pragma unroll
  for (int p = 0; p < 4; ++p){                      // refill for t+2
    zrw[p] = xzr[ob[p] + pof];
    xhw[p] = xh [ob[p] + pof];
  }
  BARRIER();                                        // h' visible
}

__global__ __launch_bounds__(256, 1) void gru_recb(
    const float* __restrict__ Uz, const float* __restrict__ Ur, const float* __restrict__ Uh,
    const int* __restrict__ lengths,
    const unsigned int* xzr,            // aliases `out` (packed bf16 xz|xr)
    const unsigned short* __restrict__ xh,
    float* out)
{
  __shared__ __align__(16) __bf16 hbf[8][136];
  __shared__ __align__(16) __bf16 rhbf[8][136];

  const int tid = threadIdx.x;
  const int w = tid >> 6, l = tid & 63;
  const int g8   = l >> 4;
  const int c    = l & 15;
  const int tsel = g8 >> 1;             // which of the wave's 2 col-tiles
  const int bsel = g8 & 1;              // batch half: batches 4*bsel+p
  const int row  = l & 7;               // A-frag source row (dup 8-15 -> 0-7)
  const int b0   = blockIdx.x * 8;

  int maxlen = 0;
  #pragma unroll
  for (int i = 0; i < 8; ++i){
    int L = lengths[b0 + i];
    maxlen = L > maxlen ? L : maxlen;
  }

  // U B-fragments for the wave's two 16-unit col-tiles: 96 VGPRs
  bf16x8 ufz[2][4], ufr[2][4], ufh[2][4];
  #pragma unroll
  for (int T = 0; T < 2; ++T){
    const int n = 32 * w + 16 * T + c;
    #pragma unroll
    for (int ch = 0; ch < 4; ++ch){
      const int ko = ch * 32 + g8 * 8;
      ufz[T][ch] = ld_u_frag(Uz + n * H_DIM + ko);
      ufr[T][ch] = ld_u_frag(Ur + n * H_DIM + ko);
      ufh[T][ch] = ld_u_frag(Uh + n * H_DIM + ko);
    }
  }

  const int n_own = 32 * w + 16 * tsel + c;
  unsigned int ob[4];
  #pragma unroll
  for (int p = 0; p < 4; ++p)
    ob[p] = (unsigned int)(b0 + 4 * bsel + p) * TH + (unsigned int)n_own;

  // zero h tile (h0 = 0): 8*136 halves = 544 dwords
  unsigned int* hz = reinterpret_cast<unsigned int*>(&hbf[0][0]);
  hz[tid] = 0u;  hz[tid + 256] = 0u;
  if (tid < 32) hz[tid + 512] = 0u;
  float h_own[4] = {0.f, 0.f, 0.f, 0.f};
  __syncthreads();

  unsigned int* hb32 = reinterpret_cast<unsigned int*>(&hbf[0][0]);
  unsigned int* rb32 = reinterpret_cast<unsigned int*>(&rhbf[0][0]);
  const int wdw = bsel * 272 + (n_own >> 1);   // dword idx of (row 4*bsel, n)
  const bool wlane = ((l & 1) == 0);

  // 2-deep prefetch, named A/B register sets
  unsigned int zrA[4], zrB[4], xhA[4], xhB[4];
  #pragma unroll
  for (int p = 0; p < 4; ++p){
    zrA[p] = xzr[ob[p]];          zrB[p] = xzr[ob[p] + H_DIM];
    xhA[p] = xh [ob[p]];          xhB[p] = xh [ob[p] + H_DIM];
  }

  int t = 0;
  for (; t + 1 < maxlen; t += 2){
    gru_stepX(t,   row, g8, tsel, ufz, ufr, ufh, hbf, rhbf, hb32, rb32, wdw, wlane,
              xzr, xh, out, ob, zrA, xhA, h_own);
    gru_stepX(t+1, row, g8, tsel, ufz, ufr, ufh, hbf, rhbf, hb32, rb32, wdw, wlane,
              xzr, xh, out, ob, zrB, xhB, h_own);
  }
  if (t < maxlen){
    gru_stepX(t,   row, g8, tsel, ufz, ufr, ufh, hbf, rhbf, hb32, rb32, wdw, wlane,
              xzr, xh, out, ob, zrA, xhA, h_own);
  }
}

// ---- zero tail: t >= len[b] (runs after gru_recb; kernel boundary orders
//      it after the in-flight garbage stores) ----
__global__ __launch_bounds__(256) void gru_tail(
    const int* __restrict__ lengths, float* __restrict__ out)
{
  const int b = blockIdx.x >> 1;
  const int s = blockIdx.x & 1;
  const int len = lengths[b];
  const long base = (long)b * TH;
  for (long i = (long)len * H_DIM + (s * 256 + threadIdx.x) * 4;
       i < (long)T_LEN * H_DIM; i += 512 * 4){
    *reinterpret_cast<float4*>(out + base + i) = make_float4(0.f, 0.f, 0.f, 0.f);
  }
}

extern "C" void kernel_launch(void* const* d_in, const int* in_sizes, int n_in,
                              void* d_out, int out_size, void* d_ws, size_t ws_size,
                              hipStream_t stream){
  const float* x       = (const float*)d_in[0];
  const int*   lengths = (const int*)  d_in[1];
  const float* Wz = (const float*)d_in[2];
  const float* Uz = (const float*)d_in[3];
  const float* bz = (const float*)d_in[4];
  const float* Wr = (const float*)d_in[5];
  const float* Ur = (const float*)d_in[6];
  const float* br = (const float*)d_in[7];
  const float* Wh = (const float*)d_in[8];
  const float* Uh = (const float*)d_in[9];
  const float* bh = (const float*)d_in[10];

  unsigned int*   zr    = (unsigned int*)d_out;   // packed bf16 xz|xr, then h
  unsigned short* xhbuf = (unsigned short*)d_ws;  // bf16 xh

  gru_proj<<<dim3(2048), dim3(512), 0, stream>>>(x, Wz, Wr, Wh, bz, br, bh, zr, xhbuf);
  gru_recb<<<dim3(16), dim3(256), 0, stream>>>(Uz, Ur, Uh, lengths, zr, xhbuf, (float*)d_out);
  gru_tail<<<dim3(256), dim3(256), 0, stream>>>(lengths, (float*)d_out);
}

// Round 11
// 1241.125 us; speedup vs baseline: 1.6725x; 1.4483x over previous
//
#include <hip/hip_runtime.h>

// GRU: B=128, T=2048, H=128.
// K1 gru_proj: xz/xr/xh = x @ W^T + b via bf16 MFMA (verified since R1).
// K2 gru_rec8h: R6 structure (1 batch/block, 8 waves x 16 units, broadcast-A
//   MFMA, 4 independent MFMAs/gate + add tree, fast exp2/rcp, 2 lgkm-only
//   barriers/step, 2-deep prefetch, fire-and-forget stores) PLUS heater
//   blocks: grid 256, blocks 128-255 run dense FMA chains polling a
//   device-scope done-flag. Hypothesis: the uniform ~2x gap between the
//   latency model (~700cy/step) and measurement (~1390cy/step @2.4GHz
//   assumption) is DVFS downclocking on a near-idle chip; heaters hold SCLK.

#define T_LEN 2048
#define H_DIM 128

typedef __attribute__((ext_vector_type(8))) __bf16 bf16x8;
typedef __attribute__((ext_vector_type(4))) float f32x4;

// raw barrier: drains LDS ops (cross-wave visibility) but NOT vmcnt. [m201]
#define BARRIER() asm volatile("s_waitcnt lgkmcnt(0)\n\ts_barrier" ::: "memory")

__device__ int g_done;                       // re-zeroed every launch

__device__ __forceinline__ unsigned short f2bf_bits(float f){
  __bf16 b = (__bf16)f;                     // fptrunc, RNE
  return __builtin_bit_cast(unsigned short, b);
}
__device__ __forceinline__ float bf2f(unsigned short s){
  unsigned int u = ((unsigned int)s) << 16;
  return __builtin_bit_cast(float, u);
}
__device__ __forceinline__ unsigned int pack_bf16_rne(float lo, float hi){
  return (unsigned int)f2bf_bits(lo) | (((unsigned int)f2bf_bits(hi)) << 16);
}
// hardware v_exp_f32 / v_rcp_f32 (no precise-division sequence)
__device__ __forceinline__ float sigm(float x){
  float e = __builtin_amdgcn_exp2f(-1.4426950408889634f * x);
  return __builtin_amdgcn_rcpf(1.0f + e);
}
__device__ __forceinline__ float tanh_fast(float x){
  float e = __builtin_amdgcn_exp2f(2.8853900817779268f * x);  // e^(2x)
  return 1.0f - 2.0f * __builtin_amdgcn_rcpf(e + 1.0f);       // inf-safe
}
// lane <- lane^1 value (quad_perm [1,0,3,2] = 0xB1); run in ALL lanes
__device__ __forceinline__ float dpp_xor1(float x){
  int r = __builtin_amdgcn_update_dpp(0, __builtin_bit_cast(int, x),
                                      0xB1, 0xF, 0xF, true);
  return __builtin_bit_cast(float, r);
}

// ---------------- projection GEMM (unchanged, verified) ----------------

__device__ __forceinline__ void stage_mat128(const float* __restrict__ src,
                                             __bf16 (*dst)[136], int tid){
  #pragma unroll
  for (int rep = 0; rep < 8; ++rep){
    int fi = rep * 2048 + tid * 4;
    float4 v = *reinterpret_cast<const float4*>(src + fi);
    int m = fi >> 7;
    int k = fi & 127;
    unsigned long long pk =
        (unsigned long long)f2bf_bits(v.x)
      | ((unsigned long long)f2bf_bits(v.y) << 16)
      | ((unsigned long long)f2bf_bits(v.z) << 32)
      | ((unsigned long long)f2bf_bits(v.w) << 48);
    *reinterpret_cast<unsigned long long*>(&dst[m][k]) = pk;
  }
}

__global__ __launch_bounds__(512, 2) void gru_proj(
    const float* __restrict__ x,
    const float* __restrict__ Wz, const float* __restrict__ Wr, const float* __restrict__ Wh,
    const float* __restrict__ bz, const float* __restrict__ br, const float* __restrict__ bh,
    unsigned int* __restrict__ out_zr, unsigned short* __restrict__ out_h)
{
  __shared__ __bf16 xs[128][136];
  __shared__ __bf16 wsh[3][128][136];

  const int tid = threadIdx.x;
  const long Mbase = (long)blockIdx.x * 128;

  stage_mat128(x + Mbase * H_DIM, xs, tid);
  stage_mat128(Wz, wsh[0], tid);
  stage_mat128(Wr, wsh[1], tid);
  stage_mat128(Wh, wsh[2], tid);
  __syncthreads();

  const int w  = tid >> 6, l = tid & 63;
  const int ml = l & 15;
  const int kl = (l >> 4) * 8;
  const int n  = w * 16 + ml;

  bf16x8 bfr[3][4];
  #pragma unroll
  for (int g = 0; g < 3; ++g)
    #pragma unroll
    for (int kk = 0; kk < 4; ++kk)
      bfr[g][kk] = *reinterpret_cast<const bf16x8*>(&wsh[g][n][kk * 32 + kl]);

  const float bzv = bz[n], brv = br[n], bhv = bh[n];

  f32x4 acc[8][3];
  #pragma unroll
  for (int mt = 0; mt < 8; ++mt)
    #pragma unroll
    for (int g = 0; g < 3; ++g)
      acc[mt][g] = (f32x4){0.f, 0.f, 0.f, 0.f};

  #pragma unroll
  for (int mt = 0; mt < 8; ++mt){
    #pragma unroll
    for (int kk = 0; kk < 4; ++kk){
      bf16x8 a = *reinterpret_cast<const bf16x8*>(&xs[mt * 16 + ml][kk * 32 + kl]);
      acc[mt][0] = __builtin_amdgcn_mfma_f32_16x16x32_bf16(a, bfr[0][kk], acc[mt][0], 0, 0, 0);
      acc[mt][1] = __builtin_amdgcn_mfma_f32_16x16x32_bf16(a, bfr[1][kk], acc[mt][1], 0, 0, 0);
      acc[mt][2] = __builtin_amdgcn_mfma_f32_16x16x32_bf16(a, bfr[2][kk], acc[mt][2], 0, 0, 0);
    }
  }

  #pragma unroll
  for (int mt = 0; mt < 8; ++mt){
    #pragma unroll
    for (int p = 0; p < 4; ++p){
      long row = Mbase + mt * 16 + (l >> 4) * 4 + p;
      float vz = acc[mt][0][p] + bzv;
      float vr = acc[mt][1][p] + brv;
      float vh = acc[mt][2][p] + bhv;
      unsigned int word = (unsigned int)f2bf_bits(vz)
                        | (((unsigned int)f2bf_bits(vr)) << 16);
      out_zr[row * H_DIM + n] = word;
      out_h [row * H_DIM + n] = f2bf_bits(vh);
    }
  }
}

// ---------------- flag init (per-launch reset; kernel-boundary ordered) ----

__global__ void gru_init(){
  __hip_atomic_store(&g_done, 0, __ATOMIC_RELAXED, __HIP_MEMORY_SCOPE_AGENT);
}

// -------- recurrence: broadcast-A MFMA, 8 waves, 1 batch/block + heaters ----

__device__ __forceinline__ bf16x8 ld_u_frag(const float* p){
  float4 a = *reinterpret_cast<const float4*>(p);
  float4 b = *reinterpret_cast<const float4*>(p + 4);
  bf16x8 r;
  r[0]=(__bf16)a.x; r[1]=(__bf16)a.y; r[2]=(__bf16)a.z; r[3]=(__bf16)a.w;
  r[4]=(__bf16)b.x; r[5]=(__bf16)b.y; r[6]=(__bf16)b.z; r[7]=(__bf16)b.w;
  return r;
}

#define MFMA(A, B, C) __builtin_amdgcn_mfma_f32_16x16x32_bf16(A, B, C, 0, 0, 0)

__device__ __forceinline__ void gru_step8(
    int t, int ub, int g8, int l, int w,
    const bf16x8* ufz, const bf16x8* ufr, const bf16x8* ufh,
    __bf16* hx, __bf16* rhx,
    const unsigned int* xzr, const unsigned short* xh, float* out,
    unsigned int& zrw, unsigned short& xhw, float& h_own)
{
  const f32x4 zero = (f32x4){0.f, 0.f, 0.f, 0.f};
  const int tp = (t + 2 < T_LEN) ? t + 2 : T_LEN - 1;
  const bool wr = ((l & 1) == 0) & (l < 16);

  // ---- phase A: r gate only; 4 independent MFMAs + add tree ----
  bf16x8 a0 = *reinterpret_cast<const bf16x8*>(&hx[      g8 * 8]);
  bf16x8 a1 = *reinterpret_cast<const bf16x8*>(&hx[32  + g8 * 8]);
  bf16x8 a2 = *reinterpret_cast<const bf16x8*>(&hx[64  + g8 * 8]);
  bf16x8 a3 = *reinterpret_cast<const bf16x8*>(&hx[96  + g8 * 8]);
  f32x4 r0 = MFMA(a0, ufr[0], zero);
  f32x4 r1 = MFMA(a1, ufr[1], zero);
  f32x4 r2 = MFMA(a2, ufr[2], zero);
  f32x4 r3 = MFMA(a3, ufr[3], zero);

  float xzv = bf2f((unsigned short)(zrw & 0xffffu));   // keep for phase B
  float xrv = bf2f((unsigned short)(zrw >> 16));
  zrw = xzr[ub + tp * H_DIM];                           // refill for t+2

  float rg = sigm(xrv + ((r0[0] + r1[0]) + (r2[0] + r3[0])));
  float rh  = rg * h_own;
  float rhn = dpp_xor1(rh);                             // all lanes (exec!)
  if (wr)
    *reinterpret_cast<unsigned int*>(&rhx[w * 16 + (l & 14)]) = pack_bf16_rne(rh, rhn);
  BARRIER();                                            // rh visible

  // ---- phase B: z (register h frags; hides under rh read) + h~ + update ----
  bf16x8 b0 = *reinterpret_cast<const bf16x8*>(&rhx[      g8 * 8]);
  bf16x8 b1 = *reinterpret_cast<const bf16x8*>(&rhx[32  + g8 * 8]);
  bf16x8 b2 = *reinterpret_cast<const bf16x8*>(&rhx[64  + g8 * 8]);
  bf16x8 b3 = *reinterpret_cast<const bf16x8*>(&rhx[96  + g8 * 8]);
  f32x4 z0 = MFMA(a0, ufz[0], zero);
  f32x4 z1 = MFMA(a1, ufz[1], zero);
  f32x4 z2 = MFMA(a2, ufz[2], zero);
  f32x4 z3 = MFMA(a3, ufz[3], zero);
  f32x4 h0 = MFMA(b0, ufh[0], zero);
  f32x4 h1 = MFMA(b1, ufh[1], zero);
  f32x4 h2 = MFMA(b2, ufh[2], zero);
  f32x4 h3 = MFMA(b3, ufh[3], zero);

  float zg = sigm(xzv + ((z0[0] + z1[0]) + (z2[0] + z3[0])));
  float hc = tanh_fast(bf2f(xhw) + ((h0[0] + h1[0]) + (h2[0] + h3[0])));
  float hn = fmaf(zg, hc - h_own, h_own);               // (1-z)h + z*hc
  h_own = hn;
  float hnn = dpp_xor1(hn);
  if (wr)
    *reinterpret_cast<unsigned int*>(&hx[w * 16 + (l & 14)]) = pack_bf16_rne(hn, hnn);
  if (l < 16)
    out[ub + t * H_DIM] = hn;                           // fire-and-forget
  xhw = xh[ub + tp * H_DIM];                            // refill for t+2
  BARRIER();                                            // h' visible
}

__global__ __launch_bounds__(512, 1) void gru_rec8h(
    const float* __restrict__ Uz, const float* __restrict__ Ur, const float* __restrict__ Uh,
    const int* __restrict__ lengths,
    const unsigned int* xzr,            // aliases `out` (packed bf16 xz|xr)
    const unsigned short* __restrict__ xh,
    float* out)
{
  __shared__ __align__(16) __bf16 hx[H_DIM];
  __shared__ __align__(16) __bf16 rhx[H_DIM];

  // ---- heater blocks: hold chip activity high so SCLK stays boosted ----
  if (blockIdx.x >= 128){
    float f0=1.f,f1=1.f,f2=1.f,f3=1.f,f4=1.f,f5=1.f,f6=1.f,f7=1.f;
    while (__hip_atomic_load(&g_done, __ATOMIC_RELAXED,
                             __HIP_MEMORY_SCOPE_AGENT) < 128){
      #pragma unroll
      for (int i = 0; i < 64; ++i){
        f0 = fmaf(f0, 1.0f, 1e-20f);  f1 = fmaf(f1, 1.0f, 1e-20f);
        f2 = fmaf(f2, 1.0f, 1e-20f);  f3 = fmaf(f3, 1.0f, 1e-20f);
        f4 = fmaf(f4, 1.0f, 1e-20f);  f5 = fmaf(f5, 1.0f, 1e-20f);
        f6 = fmaf(f6, 1.0f, 1e-20f);  f7 = fmaf(f7, 1.0f, 1e-20f);
      }
    }
    asm volatile("" :: "v"(f0),"v"(f1),"v"(f2),"v"(f3),
                       "v"(f4),"v"(f5),"v"(f6),"v"(f7));
    return;
  }

  const int tid = threadIdx.x;
  const int w = tid >> 6, l = tid & 63;
  const int g8 = l >> 4;                // k-slice within each 32-k block
  const int u  = w * 16 + (l & 15);     // owned unit (C col)
  const int b  = blockIdx.x;
  const int len = lengths[b];

  // U B-fragments: 3 gates x 4 k-steps x 4 VGPR = 48 VGPRs
  bf16x8 ufz[4], ufr[4], ufh[4];
  #pragma unroll
  for (int kk = 0; kk < 4; ++kk){
    const int ko = kk * 32 + g8 * 8;
    ufz[kk] = ld_u_frag(Uz + u * H_DIM + ko);
    ufr[kk] = ld_u_frag(Ur + u * H_DIM + ko);
    ufh[kk] = ld_u_frag(Uh + u * H_DIM + ko);
  }

  if (tid < 64) reinterpret_cast<unsigned int*>(hx)[tid] = 0u;  // h0 = 0
  float h_own = 0.f;
  __syncthreads();

  const int ub = b * (T_LEN * H_DIM) + u;   // element offset of (b, t=0, u)

  // 2-deep prefetch, named regs
  unsigned int  zrA, zrB;
  unsigned short xhA, xhB;
  zrA = xzr[ub];             xhA = xh[ub];
  zrB = xzr[ub + H_DIM];     xhB = xh[ub + H_DIM];

  int t = 0;
  for (; t + 1 < len; t += 2){
    gru_step8(t,   ub, g8, l, w, ufz, ufr, ufh, hx, rhx, xzr, xh, out, zrA, xhA, h_own);
    gru_step8(t+1, ub, g8, l, w, ufz, ufr, ufh, hx, rhx, xzr, xh, out, zrB, xhB, h_own);
  }
  if (t < len){
    gru_step8(t,   ub, g8, l, w, ufz, ufr, ufh, hx, rhx, xzr, xh, out, zrA, xhA, h_own);
  }

  // masked region: exact zeros for t >= len (disjoint from h-stores)
  const long base = (long)b * (T_LEN * H_DIM);
  for (long i = (long)len * H_DIM + tid * 4; i < (long)T_LEN * H_DIM; i += 512 * 4){
    *reinterpret_cast<float4*>(out + base + i) = make_float4(0.f, 0.f, 0.f, 0.f);
  }

  // signal heaters
  if (tid == 0)
    __hip_atomic_fetch_add(&g_done, 1, __ATOMIC_RELAXED, __HIP_MEMORY_SCOPE_AGENT);
}

extern "C" void kernel_launch(void* const* d_in, const int* in_sizes, int n_in,
                              void* d_out, int out_size, void* d_ws, size_t ws_size,
                              hipStream_t stream){
  const float* x       = (const float*)d_in[0];
  const int*   lengths = (const int*)  d_in[1];
  const float* Wz = (const float*)d_in[2];
  const float* Uz = (const float*)d_in[3];
  const float* bz = (const float*)d_in[4];
  const float* Wr = (const float*)d_in[5];
  const float* Ur = (const float*)d_in[6];
  const float* br = (const float*)d_in[7];
  const float* Wh = (const float*)d_in[8];
  const float* Uh = (const float*)d_in[9];
  const float* bh = (const float*)d_in[10];

  unsigned int*   zr    = (unsigned int*)d_out;   // packed bf16 xz|xr, then h
  unsigned short* xhbuf = (unsigned short*)d_ws;  // bf16 xh

  gru_proj<<<dim3(2048), dim3(512), 0, stream>>>(x, Wz, Wr, Wh, bz, br, bh, zr, xhbuf);
  gru_init<<<dim3(1), dim3(1), 0, stream>>>();
  gru_rec8h<<<dim3(256), dim3(512), 0, stream>>>(Uz, Ur, Uh, lengths, zr, xhbuf, (float*)d_out);
}

// Round 12
// 1083.964 us; speedup vs baseline: 1.9150x; 1.1450x over previous
//
#include <hip/hip_runtime.h>

// GRU: B=128, T=2048, H=128.
// K1 gru_proj: xz/xr/xh = x @ W^T + b via bf16 MFMA (verified since R1).
// K2 gru_rec8p: R6 structure (1 batch/block x 128 blocks, 8 waves x 16 units,
//   broadcast-A MFMA, 4 independent MFMAs/gate + add tree, fast exp2/rcp,
//   2 lgkm-only barriers/step, fire-and-forget stores) with FOUR-deep global
//   prefetch (named reg sets A-D). vmcnt retires IN ORDER: with 2-deep
//   prefetch, consuming a load waited transitively on older ~900cy HBM
//   misses + store retires every step. 4-deep gives >4 steps of slack.

#define T_LEN 2048
#define H_DIM 128

typedef __attribute__((ext_vector_type(8))) __bf16 bf16x8;
typedef __attribute__((ext_vector_type(4))) float f32x4;

// raw barrier: drains LDS ops (cross-wave visibility) but NOT vmcnt. [m201]
#define BARRIER() asm volatile("s_waitcnt lgkmcnt(0)\n\ts_barrier" ::: "memory")

__device__ __forceinline__ unsigned short f2bf_bits(float f){
  __bf16 b = (__bf16)f;                     // fptrunc, RNE
  return __builtin_bit_cast(unsigned short, b);
}
__device__ __forceinline__ float bf2f(unsigned short s){
  unsigned int u = ((unsigned int)s) << 16;
  return __builtin_bit_cast(float, u);
}
__device__ __forceinline__ unsigned int pack_bf16_rne(float lo, float hi){
  return (unsigned int)f2bf_bits(lo) | (((unsigned int)f2bf_bits(hi)) << 16);
}
// hardware v_exp_f32 / v_rcp_f32 (no precise-division sequence)
__device__ __forceinline__ float sigm(float x){
  float e = __builtin_amdgcn_exp2f(-1.4426950408889634f * x);
  return __builtin_amdgcn_rcpf(1.0f + e);
}
__device__ __forceinline__ float tanh_fast(float x){
  float e = __builtin_amdgcn_exp2f(2.8853900817779268f * x);  // e^(2x)
  return 1.0f - 2.0f * __builtin_amdgcn_rcpf(e + 1.0f);       // inf-safe
}
// lane <- lane^1 value (quad_perm [1,0,3,2] = 0xB1); run in ALL lanes
__device__ __forceinline__ float dpp_xor1(float x){
  int r = __builtin_amdgcn_update_dpp(0, __builtin_bit_cast(int, x),
                                      0xB1, 0xF, 0xF, true);
  return __builtin_bit_cast(float, r);
}

// ---------------- projection GEMM (unchanged, verified) ----------------

__device__ __forceinline__ void stage_mat128(const float* __restrict__ src,
                                             __bf16 (*dst)[136], int tid){
  #pragma unroll
  for (int rep = 0; rep < 8; ++rep){
    int fi = rep * 2048 + tid * 4;
    float4 v = *reinterpret_cast<const float4*>(src + fi);
    int m = fi >> 7;
    int k = fi & 127;
    unsigned long long pk =
        (unsigned long long)f2bf_bits(v.x)
      | ((unsigned long long)f2bf_bits(v.y) << 16)
      | ((unsigned long long)f2bf_bits(v.z) << 32)
      | ((unsigned long long)f2bf_bits(v.w) << 48);
    *reinterpret_cast<unsigned long long*>(&dst[m][k]) = pk;
  }
}

__global__ __launch_bounds__(512, 2) void gru_proj(
    const float* __restrict__ x,
    const float* __restrict__ Wz, const float* __restrict__ Wr, const float* __restrict__ Wh,
    const float* __restrict__ bz, const float* __restrict__ br, const float* __restrict__ bh,
    unsigned int* __restrict__ out_zr, unsigned short* __restrict__ out_h)
{
  __shared__ __bf16 xs[128][136];
  __shared__ __bf16 wsh[3][128][136];

  const int tid = threadIdx.x;
  const long Mbase = (long)blockIdx.x * 128;

  stage_mat128(x + Mbase * H_DIM, xs, tid);
  stage_mat128(Wz, wsh[0], tid);
  stage_mat128(Wr, wsh[1], tid);
  stage_mat128(Wh, wsh[2], tid);
  __syncthreads();

  const int w  = tid >> 6, l = tid & 63;
  const int ml = l & 15;
  const int kl = (l >> 4) * 8;
  const int n  = w * 16 + ml;

  bf16x8 bfr[3][4];
  #pragma unroll
  for (int g = 0; g < 3; ++g)
    #pragma unroll
    for (int kk = 0; kk < 4; ++kk)
      bfr[g][kk] = *reinterpret_cast<const bf16x8*>(&wsh[g][n][kk * 32 + kl]);

  const float bzv = bz[n], brv = br[n], bhv = bh[n];

  f32x4 acc[8][3];
  #pragma unroll
  for (int mt = 0; mt < 8; ++mt)
    #pragma unroll
    for (int g = 0; g < 3; ++g)
      acc[mt][g] = (f32x4){0.f, 0.f, 0.f, 0.f};

  #pragma unroll
  for (int mt = 0; mt < 8; ++mt){
    #pragma unroll
    for (int kk = 0; kk < 4; ++kk){
      bf16x8 a = *reinterpret_cast<const bf16x8*>(&xs[mt * 16 + ml][kk * 32 + kl]);
      acc[mt][0] = __builtin_amdgcn_mfma_f32_16x16x32_bf16(a, bfr[0][kk], acc[mt][0], 0, 0, 0);
      acc[mt][1] = __builtin_amdgcn_mfma_f32_16x16x32_bf16(a, bfr[1][kk], acc[mt][1], 0, 0, 0);
      acc[mt][2] = __builtin_amdgcn_mfma_f32_16x16x32_bf16(a, bfr[2][kk], acc[mt][2], 0, 0, 0);
    }
  }

  #pragma unroll
  for (int mt = 0; mt < 8; ++mt){
    #pragma unroll
    for (int p = 0; p < 4; ++p){
      long row = Mbase + mt * 16 + (l >> 4) * 4 + p;
      float vz = acc[mt][0][p] + bzv;
      float vr = acc[mt][1][p] + brv;
      float vh = acc[mt][2][p] + bhv;
      unsigned int word = (unsigned int)f2bf_bits(vz)
                        | (((unsigned int)f2bf_bits(vr)) << 16);
      out_zr[row * H_DIM + n] = word;
      out_h [row * H_DIM + n] = f2bf_bits(vh);
    }
  }
}

// -------- recurrence: broadcast-A MFMA, 8 waves, 4-deep prefetch ------------

__device__ __forceinline__ bf16x8 ld_u_frag(const float* p){
  float4 a = *reinterpret_cast<const float4*>(p);
  float4 b = *reinterpret_cast<const float4*>(p + 4);
  bf16x8 r;
  r[0]=(__bf16)a.x; r[1]=(__bf16)a.y; r[2]=(__bf16)a.z; r[3]=(__bf16)a.w;
  r[4]=(__bf16)b.x; r[5]=(__bf16)b.y; r[6]=(__bf16)b.z; r[7]=(__bf16)b.w;
  return r;
}

#define MFMA(A, B, C) __builtin_amdgcn_mfma_f32_16x16x32_bf16(A, B, C, 0, 0, 0)

__device__ __forceinline__ void gru_step8(
    int t, int ub, int g8, int l, int w,
    const bf16x8* ufz, const bf16x8* ufr, const bf16x8* ufh,
    __bf16* hx, __bf16* rhx,
    const unsigned int* xzr, const unsigned short* xh, float* out,
    unsigned int& zrw, unsigned short& xhw, float& h_own)
{
  const f32x4 zero = (f32x4){0.f, 0.f, 0.f, 0.f};
  const int tp = (t + 4 < T_LEN) ? t + 4 : T_LEN - 1;   // refill slot (4-deep)
  const bool wr = ((l & 1) == 0) & (l < 16);

  // ---- phase A: r gate only; 4 independent MFMAs + add tree ----
  bf16x8 a0 = *reinterpret_cast<const bf16x8*>(&hx[      g8 * 8]);
  bf16x8 a1 = *reinterpret_cast<const bf16x8*>(&hx[32  + g8 * 8]);
  bf16x8 a2 = *reinterpret_cast<const bf16x8*>(&hx[64  + g8 * 8]);
  bf16x8 a3 = *reinterpret_cast<const bf16x8*>(&hx[96  + g8 * 8]);
  f32x4 r0 = MFMA(a0, ufr[0], zero);
  f32x4 r1 = MFMA(a1, ufr[1], zero);
  f32x4 r2 = MFMA(a2, ufr[2], zero);
  f32x4 r3 = MFMA(a3, ufr[3], zero);

  // consume this step's prefetched inputs, then refill BOTH for t+4
  float xzv = bf2f((unsigned short)(zrw & 0xffffu));
  float xrv = bf2f((unsigned short)(zrw >> 16));
  float xhv = bf2f(xhw);                                // early extract
  zrw = xzr[ub + tp * H_DIM];
  xhw = xh [ub + tp * H_DIM];

  float rg = sigm(xrv + ((r0[0] + r1[0]) + (r2[0] + r3[0])));
  float rh  = rg * h_own;
  float rhn = dpp_xor1(rh);                             // all lanes (exec!)
  if (wr)
    *reinterpret_cast<unsigned int*>(&rhx[w * 16 + (l & 14)]) = pack_bf16_rne(rh, rhn);
  BARRIER();                                            // rh visible

  // ---- phase B: z (register h frags; hides under rh read) + h~ + update ----
  bf16x8 b0 = *reinterpret_cast<const bf16x8*>(&rhx[      g8 * 8]);
  bf16x8 b1 = *reinterpret_cast<const bf16x8*>(&rhx[32  + g8 * 8]);
  bf16x8 b2 = *reinterpret_cast<const bf16x8*>(&rhx[64  + g8 * 8]);
  bf16x8 b3 = *reinterpret_cast<const bf16x8*>(&rhx[96  + g8 * 8]);
  f32x4 z0 = MFMA(a0, ufz[0], zero);
  f32x4 z1 = MFMA(a1, ufz[1], zero);
  f32x4 z2 = MFMA(a2, ufz[2], zero);
  f32x4 z3 = MFMA(a3, ufz[3], zero);
  f32x4 h0 = MFMA(b0, ufh[0], zero);
  f32x4 h1 = MFMA(b1, ufh[1], zero);
  f32x4 h2 = MFMA(b2, ufh[2], zero);
  f32x4 h3 = MFMA(b3, ufh[3], zero);

  float zg = sigm(xzv + ((z0[0] + z1[0]) + (z2[0] + z3[0])));
  float hc = tanh_fast(xhv + ((h0[0] + h1[0]) + (h2[0] + h3[0])));
  float hn = fmaf(zg, hc - h_own, h_own);               // (1-z)h + z*hc
  h_own = hn;
  float hnn = dpp_xor1(hn);
  if (wr)
    *reinterpret_cast<unsigned int*>(&hx[w * 16 + (l & 14)]) = pack_bf16_rne(hn, hnn);
  if (l < 16)
    out[ub + t * H_DIM] = hn;                           // fire-and-forget
  BARRIER();                                            // h' visible
}

__global__ __launch_bounds__(512, 1) void gru_rec8p(
    const float* __restrict__ Uz, const float* __restrict__ Ur, const float* __restrict__ Uh,
    const int* __restrict__ lengths,
    const unsigned int* xzr,            // aliases `out` (packed bf16 xz|xr)
    const unsigned short* __restrict__ xh,
    float* out)
{
  __shared__ __align__(16) __bf16 hx[H_DIM];
  __shared__ __align__(16) __bf16 rhx[H_DIM];

  const int tid = threadIdx.x;
  const int w = tid >> 6, l = tid & 63;
  const int g8 = l >> 4;                // k-slice within each 32-k block
  const int u  = w * 16 + (l & 15);     // owned unit (C col)
  const int b  = blockIdx.x;
  const int len = lengths[b];

  // U B-fragments: 3 gates x 4 k-steps x 4 VGPR = 48 VGPRs
  bf16x8 ufz[4], ufr[4], ufh[4];
  #pragma unroll
  for (int kk = 0; kk < 4; ++kk){
    const int ko = kk * 32 + g8 * 8;
    ufz[kk] = ld_u_frag(Uz + u * H_DIM + ko);
    ufr[kk] = ld_u_frag(Ur + u * H_DIM + ko);
    ufh[kk] = ld_u_frag(Uh + u * H_DIM + ko);
  }

  if (tid < 64) reinterpret_cast<unsigned int*>(hx)[tid] = 0u;  // h0 = 0
  float h_own = 0.f;
  __syncthreads();

  const int ub = b * (T_LEN * H_DIM) + u;   // element offset of (b, t=0, u)

  // 4-deep prefetch, named register sets (slots t, t+1, t+2, t+3)
  unsigned int  zrA = xzr[ub];
  unsigned int  zrB = xzr[ub + 1 * H_DIM];
  unsigned int  zrC = xzr[ub + 2 * H_DIM];
  unsigned int  zrD = xzr[ub + 3 * H_DIM];
  unsigned short xhA = xh[ub];
  unsigned short xhB = xh[ub + 1 * H_DIM];
  unsigned short xhC = xh[ub + 2 * H_DIM];
  unsigned short xhD = xh[ub + 3 * H_DIM];

  int t = 0;
  for (; t + 3 < len; t += 4){
    gru_step8(t,   ub, g8, l, w, ufz, ufr, ufh, hx, rhx, xzr, xh, out, zrA, xhA, h_own);
    gru_step8(t+1, ub, g8, l, w, ufz, ufr, ufh, hx, rhx, xzr, xh, out, zrB, xhB, h_own);
    gru_step8(t+2, ub, g8, l, w, ufz, ufr, ufh, hx, rhx, xzr, xh, out, zrC, xhC, h_own);
    gru_step8(t+3, ub, g8, l, w, ufz, ufr, ufh, hx, rhx, xzr, xh, out, zrD, xhD, h_own);
  }
  if (t < len)
    gru_step8(t,   ub, g8, l, w, ufz, ufr, ufh, hx, rhx, xzr, xh, out, zrA, xhA, h_own);
  if (t + 1 < len)
    gru_step8(t+1, ub, g8, l, w, ufz, ufr, ufh, hx, rhx, xzr, xh, out, zrB, xhB, h_own);
  if (t + 2 < len)
    gru_step8(t+2, ub, g8, l, w, ufz, ufr, ufh, hx, rhx, xzr, xh, out, zrC, xhC, h_own);

  // masked region: exact zeros for t >= len (disjoint from h-stores)
  const long base = (long)b * (T_LEN * H_DIM);
  for (long i = (long)len * H_DIM + tid * 4; i < (long)T_LEN * H_DIM; i += 512 * 4){
    *reinterpret_cast<float4*>(out + base + i) = make_float4(0.f, 0.f, 0.f, 0.f);
  }
}

extern "C" void kernel_launch(void* const* d_in, const int* in_sizes, int n_in,
                              void* d_out, int out_size, void* d_ws, size_t ws_size,
                              hipStream_t stream){
  const float* x       = (const float*)d_in[0];
  const int*   lengths = (const int*)  d_in[1];
  const float* Wz = (const float*)d_in[2];
  const float* Uz = (const float*)d_in[3];
  const float* bz = (const float*)d_in[4];
  const float* Wr = (const float*)d_in[5];
  const float* Ur = (const float*)d_in[6];
  const float* br = (const float*)d_in[7];
  const float* Wh = (const float*)d_in[8];
  const float* Uh = (const float*)d_in[9];
  const float* bh = (const float*)d_in[10];

  unsigned int*   zr    = (unsigned int*)d_out;   // packed bf16 xz|xr, then h
  unsigned short* xhbuf = (unsigned short*)d_ws;  // bf16 xh

  gru_proj<<<dim3(2048), dim3(512), 0, stream>>>(x, Wz, Wr, Wh, bz, br, bh, zr, xhbuf);
  gru_rec8p<<<dim3(128), dim3(512), 0, stream>>>(Uz, Ur, Uh, lengths, zr, xhbuf, (float*)d_out);
}

// Round 13
// 971.634 us; speedup vs baseline: 2.1363x; 1.1156x over previous
//
#include <hip/hip_runtime.h>

// GRU: B=128, T=2048, H=128.
// K1 gru_proj: xz/xr/xh = x @ W^T + b via bf16 MFMA. Gate inputs PRESCALED:
//   xz,xr by -log2(e) (sigmoid as rcp(1+exp2(x))), xh by +2*log2(e)
//   (tanh as fma(-2, rcp(exp2(y)+1), 1)). U-frags likewise scaled at load.
// K2 gru_rec8q: R12 structure (1 batch/block x 128 blocks, 8 waves x 16
//   units, broadcast-A MFMA, 4 independent MFMAs/gate + add tree, 2
//   lgkm-only barriers/step, fire-and-forget stores) with:
//   - 6-deep named-register global prefetch (in-order vmcnt slack)
//   - refills issued AFTER each phase's LDS write (covers write latency)
//   - direct exec-masked ds_write_b16 exchange (no dpp/pack)

#define T_LEN 2048
#define H_DIM 128

typedef __attribute__((ext_vector_type(8))) __bf16 bf16x8;
typedef __attribute__((ext_vector_type(4))) float f32x4;

// raw barrier: drains LDS ops (cross-wave visibility) but NOT vmcnt. [m201]
#define BARRIER() asm volatile("s_waitcnt lgkmcnt(0)\n\ts_barrier" ::: "memory")

#define KNEG -1.4426950408889634f   // -log2(e): z,r prescale
#define KPOS  2.8853900817779268f   // 2*log2(e): h prescale

__device__ __forceinline__ unsigned short f2bf_bits(float f){
  __bf16 b = (__bf16)f;                     // fptrunc, RNE
  return __builtin_bit_cast(unsigned short, b);
}
__device__ __forceinline__ float bf2f(unsigned short s){
  unsigned int u = ((unsigned int)s) << 16;
  return __builtin_bit_cast(float, u);
}
// prescaled sigmoid: input already -log2e * logit
__device__ __forceinline__ float sigm_pre(float x){
  return __builtin_amdgcn_rcpf(1.0f + __builtin_amdgcn_exp2f(x));
}
// prescaled tanh: input already 2*log2e * arg
__device__ __forceinline__ float tanh_pre(float y){
  float t = __builtin_amdgcn_rcpf(__builtin_amdgcn_exp2f(y) + 1.0f);
  return fmaf(-2.0f, t, 1.0f);              // inf-safe: ->1 / ->-1
}

// ---------------- projection GEMM (R1-verified + prescale epilogue) --------

__device__ __forceinline__ void stage_mat128(const float* __restrict__ src,
                                             __bf16 (*dst)[136], int tid){
  #pragma unroll
  for (int rep = 0; rep < 8; ++rep){
    int fi = rep * 2048 + tid * 4;
    float4 v = *reinterpret_cast<const float4*>(src + fi);
    int m = fi >> 7;
    int k = fi & 127;
    unsigned long long pk =
        (unsigned long long)f2bf_bits(v.x)
      | ((unsigned long long)f2bf_bits(v.y) << 16)
      | ((unsigned long long)f2bf_bits(v.z) << 32)
      | ((unsigned long long)f2bf_bits(v.w) << 48);
    *reinterpret_cast<unsigned long long*>(&dst[m][k]) = pk;
  }
}

__global__ __launch_bounds__(512, 2) void gru_proj(
    const float* __restrict__ x,
    const float* __restrict__ Wz, const float* __restrict__ Wr, const float* __restrict__ Wh,
    const float* __restrict__ bz, const float* __restrict__ br, const float* __restrict__ bh,
    unsigned int* __restrict__ out_zr, unsigned short* __restrict__ out_h)
{
  __shared__ __bf16 xs[128][136];
  __shared__ __bf16 wsh[3][128][136];

  const int tid = threadIdx.x;
  const long Mbase = (long)blockIdx.x * 128;

  stage_mat128(x + Mbase * H_DIM, xs, tid);
  stage_mat128(Wz, wsh[0], tid);
  stage_mat128(Wr, wsh[1], tid);
  stage_mat128(Wh, wsh[2], tid);
  __syncthreads();

  const int w  = tid >> 6, l = tid & 63;
  const int ml = l & 15;
  const int kl = (l >> 4) * 8;
  const int n  = w * 16 + ml;

  bf16x8 bfr[3][4];
  #pragma unroll
  for (int g = 0; g < 3; ++g)
    #pragma unroll
    for (int kk = 0; kk < 4; ++kk)
      bfr[g][kk] = *reinterpret_cast<const bf16x8*>(&wsh[g][n][kk * 32 + kl]);

  const float bzv = bz[n], brv = br[n], bhv = bh[n];

  f32x4 acc[8][3];
  #pragma unroll
  for (int mt = 0; mt < 8; ++mt)
    #pragma unroll
    for (int g = 0; g < 3; ++g)
      acc[mt][g] = (f32x4){0.f, 0.f, 0.f, 0.f};

  #pragma unroll
  for (int mt = 0; mt < 8; ++mt){
    #pragma unroll
    for (int kk = 0; kk < 4; ++kk){
      bf16x8 a = *reinterpret_cast<const bf16x8*>(&xs[mt * 16 + ml][kk * 32 + kl]);
      acc[mt][0] = __builtin_amdgcn_mfma_f32_16x16x32_bf16(a, bfr[0][kk], acc[mt][0], 0, 0, 0);
      acc[mt][1] = __builtin_amdgcn_mfma_f32_16x16x32_bf16(a, bfr[1][kk], acc[mt][1], 0, 0, 0);
      acc[mt][2] = __builtin_amdgcn_mfma_f32_16x16x32_bf16(a, bfr[2][kk], acc[mt][2], 0, 0, 0);
    }
  }

  #pragma unroll
  for (int mt = 0; mt < 8; ++mt){
    #pragma unroll
    for (int p = 0; p < 4; ++p){
      long row = Mbase + mt * 16 + (l >> 4) * 4 + p;
      float vz = (acc[mt][0][p] + bzv) * KNEG;   // prescaled for sigm_pre
      float vr = (acc[mt][1][p] + brv) * KNEG;
      float vh = (acc[mt][2][p] + bhv) * KPOS;   // prescaled for tanh_pre
      unsigned int word = (unsigned int)f2bf_bits(vz)
                        | (((unsigned int)f2bf_bits(vr)) << 16);
      out_zr[row * H_DIM + n] = word;
      out_h [row * H_DIM + n] = f2bf_bits(vh);
    }
  }
}

// -------- recurrence: broadcast-A MFMA, 8 waves, 6-deep prefetch ------------

__device__ __forceinline__ bf16x8 ld_u_frag_s(const float* p, float s){
  float4 a = *reinterpret_cast<const float4*>(p);
  float4 b = *reinterpret_cast<const float4*>(p + 4);
  bf16x8 r;
  r[0]=(__bf16)(a.x*s); r[1]=(__bf16)(a.y*s); r[2]=(__bf16)(a.z*s); r[3]=(__bf16)(a.w*s);
  r[4]=(__bf16)(b.x*s); r[5]=(__bf16)(b.y*s); r[6]=(__bf16)(b.z*s); r[7]=(__bf16)(b.w*s);
  return r;
}

#define MFMA(A, B, C) __builtin_amdgcn_mfma_f32_16x16x32_bf16(A, B, C, 0, 0, 0)

__device__ __forceinline__ void gru_step8(
    int t, int ub, int g8, int l, int w,
    const bf16x8* ufz, const bf16x8* ufr, const bf16x8* ufh,
    __bf16* hx, __bf16* rhx,
    const unsigned int* xzr, const unsigned short* xh, float* out,
    unsigned int& zrw, unsigned short& xhw, float& h_own)
{
  const f32x4 zero = (f32x4){0.f, 0.f, 0.f, 0.f};
  const int tp = (t + 6 < T_LEN) ? t + 6 : T_LEN - 1;   // 6-deep refill slot
  const int u  = w * 16 + (l & 15);
  const bool own = (l < 16);

  // ---- phase A: r gate only; 4 independent MFMAs + add tree ----
  bf16x8 a0 = *reinterpret_cast<const bf16x8*>(&hx[      g8 * 8]);
  bf16x8 a1 = *reinterpret_cast<const bf16x8*>(&hx[32  + g8 * 8]);
  bf16x8 a2 = *reinterpret_cast<const bf16x8*>(&hx[64  + g8 * 8]);
  bf16x8 a3 = *reinterpret_cast<const bf16x8*>(&hx[96  + g8 * 8]);
  f32x4 r0 = MFMA(a0, ufr[0], zero);
  f32x4 r1 = MFMA(a1, ufr[1], zero);
  f32x4 r2 = MFMA(a2, ufr[2], zero);
  f32x4 r3 = MFMA(a3, ufr[3], zero);

  // consume this step's prefetched inputs (pre-refill)
  float xzv = bf2f((unsigned short)(zrw & 0xffffu));
  float xrv = bf2f((unsigned short)(zrw >> 16));
  float xhv = bf2f(xhw);

  float rg = sigm_pre(xrv + ((r0[0] + r1[0]) + (r2[0] + r3[0])));
  float rh = rg * h_own;
  if (own)
    rhx[u] = (__bf16)rh;                 // b16, 2 lanes/dword: conflict-free
  zrw = xzr[ub + tp * H_DIM];            // refill AFTER write: covers latency
  BARRIER();                             // rh visible

  // ---- phase B: z (register h frags; hides under rh read) + h~ + update ----
  bf16x8 b0 = *reinterpret_cast<const bf16x8*>(&rhx[      g8 * 8]);
  bf16x8 b1 = *reinterpret_cast<const bf16x8*>(&rhx[32  + g8 * 8]);
  bf16x8 b2 = *reinterpret_cast<const bf16x8*>(&rhx[64  + g8 * 8]);
  bf16x8 b3 = *reinterpret_cast<const bf16x8*>(&rhx[96  + g8 * 8]);
  f32x4 z0 = MFMA(a0, ufz[0], zero);
  f32x4 z1 = MFMA(a1, ufz[1], zero);
  f32x4 z2 = MFMA(a2, ufz[2], zero);
  f32x4 z3 = MFMA(a3, ufz[3], zero);
  f32x4 h0 = MFMA(b0, ufh[0], zero);
  f32x4 h1 = MFMA(b1, ufh[1], zero);
  f32x4 h2 = MFMA(b2, ufh[2], zero);
  f32x4 h3 = MFMA(b3, ufh[3], zero);

  float zg = sigm_pre(xzv + ((z0[0] + z1[0]) + (z2[0] + z3[0])));
  float hc = tanh_pre(xhv + ((h0[0] + h1[0]) + (h2[0] + h3[0])));
  float hn = fmaf(zg, hc - h_own, h_own);               // (1-z)h + z*hc
  h_own = hn;
  if (own){
    hx[u] = (__bf16)hn;
    out[ub + t * H_DIM] = hn;                           // fire-and-forget
  }
  xhw = xh[ub + tp * H_DIM];             // refill AFTER write: covers latency
  BARRIER();                             // h' visible
}

__global__ __launch_bounds__(512, 1) void gru_rec8q(
    const float* __restrict__ Uz, const float* __restrict__ Ur, const float* __restrict__ Uh,
    const int* __restrict__ lengths,
    const unsigned int* xzr,            // aliases `out` (packed bf16 xz|xr)
    const unsigned short* __restrict__ xh,
    float* out)
{
  __shared__ __align__(16) __bf16 hx[H_DIM];
  __shared__ __align__(16) __bf16 rhx[H_DIM];

  const int tid = threadIdx.x;
  const int w = tid >> 6, l = tid & 63;
  const int g8 = l >> 4;                // k-slice within each 32-k block
  const int u  = w * 16 + (l & 15);     // owned unit (C col)
  const int b  = blockIdx.x;
  const int len = lengths[b];

  // U B-fragments, prescaled: 3 gates x 4 k-steps x 4 VGPR = 48 VGPRs
  bf16x8 ufz[4], ufr[4], ufh[4];
  #pragma unroll
  for (int kk = 0; kk < 4; ++kk){
    const int ko = kk * 32 + g8 * 8;
    ufz[kk] = ld_u_frag_s(Uz + u * H_DIM + ko, KNEG);
    ufr[kk] = ld_u_frag_s(Ur + u * H_DIM + ko, KNEG);
    ufh[kk] = ld_u_frag_s(Uh + u * H_DIM + ko, KPOS);
  }

  if (tid < 64) reinterpret_cast<unsigned int*>(hx)[tid] = 0u;  // h0 = 0
  float h_own = 0.f;
  __syncthreads();

  const int ub = b * (T_LEN * H_DIM) + u;   // element offset of (b, t=0, u)

  // 6-deep prefetch, named register sets (slots t .. t+5)
  unsigned int  zrA = xzr[ub];
  unsigned int  zrB = xzr[ub + 1 * H_DIM];
  unsigned int  zrC = xzr[ub + 2 * H_DIM];
  unsigned int  zrD = xzr[ub + 3 * H_DIM];
  unsigned int  zrE = xzr[ub + 4 * H_DIM];
  unsigned int  zrF = xzr[ub + 5 * H_DIM];
  unsigned short xhA = xh[ub];
  unsigned short xhB = xh[ub + 1 * H_DIM];
  unsigned short xhC = xh[ub + 2 * H_DIM];
  unsigned short xhD = xh[ub + 3 * H_DIM];
  unsigned short xhE = xh[ub + 4 * H_DIM];
  unsigned short xhF = xh[ub + 5 * H_DIM];

  int t = 0;
  for (; t + 5 < len; t += 6){
    gru_step8(t,   ub, g8, l, w, ufz, ufr, ufh, hx, rhx, xzr, xh, out, zrA, xhA, h_own);
    gru_step8(t+1, ub, g8, l, w, ufz, ufr, ufh, hx, rhx, xzr, xh, out, zrB, xhB, h_own);
    gru_step8(t+2, ub, g8, l, w, ufz, ufr, ufh, hx, rhx, xzr, xh, out, zrC, xhC, h_own);
    gru_step8(t+3, ub, g8, l, w, ufz, ufr, ufh, hx, rhx, xzr, xh, out, zrD, xhD, h_own);
    gru_step8(t+4, ub, g8, l, w, ufz, ufr, ufh, hx, rhx, xzr, xh, out, zrE, xhE, h_own);
    gru_step8(t+5, ub, g8, l, w, ufz, ufr, ufh, hx, rhx, xzr, xh, out, zrF, xhF, h_own);
  }
  if (t < len)
    gru_step8(t,   ub, g8, l, w, ufz, ufr, ufh, hx, rhx, xzr, xh, out, zrA, xhA, h_own);
  if (t + 1 < len)
    gru_step8(t+1, ub, g8, l, w, ufz, ufr, ufh, hx, rhx, xzr, xh, out, zrB, xhB, h_own);
  if (t + 2 < len)
    gru_step8(t+2, ub, g8, l, w, ufz, ufr, ufh, hx, rhx, xzr, xh, out, zrC, xhC, h_own);
  if (t + 3 < len)
    gru_step8(t+3, ub, g8, l, w, ufz, ufr, ufh, hx, rhx, xzr, xh, out, zrD, xhD, h_own);
  if (t + 4 < len)
    gru_step8(t+4, ub, g8, l, w, ufz, ufr, ufh, hx, rhx, xzr, xh, out, zrE, xhE, h_own);

  // masked region: exact zeros for t >= len (disjoint from h-stores)
  const long base = (long)b * (T_LEN * H_DIM);
  for (long i = (long)len * H_DIM + tid * 4; i < (long)T_LEN * H_DIM; i += 512 * 4){
    *reinterpret_cast<float4*>(out + base + i) = make_float4(0.f, 0.f, 0.f, 0.f);
  }
}

extern "C" void kernel_launch(void* const* d_in, const int* in_sizes, int n_in,
                              void* d_out, int out_size, void* d_ws, size_t ws_size,
                              hipStream_t stream){
  const float* x       = (const float*)d_in[0];
  const int*   lengths = (const int*)  d_in[1];
  const float* Wz = (const float*)d_in[2];
  const float* Uz = (const float*)d_in[3];
  const float* bz = (const float*)d_in[4];
  const float* Wr = (const float*)d_in[5];
  const float* Ur = (const float*)d_in[6];
  const float* br = (const float*)d_in[7];
  const float* Wh = (const float*)d_in[8];
  const float* Uh = (const float*)d_in[9];
  const float* bh = (const float*)d_in[10];

  unsigned int*   zr    = (unsigned int*)d_out;   // packed bf16 xz|xr, then h
  unsigned short* xhbuf = (unsigned short*)d_ws;  // bf16 xh

  gru_proj<<<dim3(2048), dim3(512), 0, stream>>>(x, Wz, Wr, Wh, bz, br, bh, zr, xhbuf);
  gru_rec8q<<<dim3(128), dim3(512), 0, stream>>>(Uz, Ur, Uh, lengths, zr, xhbuf, (float*)d_out);
}